// Round 10
// baseline (49.580 us; speedup 1.0000x reference)
//
#include <hip/hip_runtime.h>
#include <stdint.h>

#define DIM_IN  4096
#define DIM_OUT 4096
#define BATCH   64
// words along dim_in: 4096/64 = 64

typedef unsigned long long u64;
typedef uint32_t u32;

#define NBLK1 2048          // compress grid (blocks of 256)
#define NTHR  (NBLK1 * 256) // 524288 threads

// ---------------------------------------------------------------------------
// Input-format detection (first 8 u32 words):
//   int32 0/1 or float 0.0/1.0 -> "word" layout (4B per bool)
//   uint8 0/1                  -> "byte" layout (1B per bool)
// Rounds 3-9: FETCH ~33.4 MB = (32 MB L2 / 67 MB masks) x 67 MB -> random-
// replacement hit rate of a word-encoded 67 MB array. Byte path kept for
// robustness (misclassify P ~ 2^-192).
// ---------------------------------------------------------------------------
__device__ __forceinline__ bool is_word_fmt(const u32* __restrict__ p) {
    bool words = true;
#pragma unroll
    for (int i = 0; i < 8; ++i) {
        u32 v = p[i];
        if (v > 1u && v != 0x3F800000u) words = false;
    }
    return words;
}

// ---------------------------------------------------------------------------
// K1 compress: PURE LINEAR grid-stride read of masks (copy-shaped, like the
// 6.3 TB/s m13 pattern) -> row-major bitmatrix rp, 67 MB -> 2 MB in one pass.
//
// Word mode: unit = uint4 (4 words). Wave W covers word indices
// [W*256, W*256+256); ballot(component c) bit L = word W*256 + 4L + c.
// Stored as rp[W*4 + c]. So rp bit layout for word index g = i*4096 + o:
//   rp[(g>>8)*4 + (g&3)] bit ((g>>2)&63).
// Byte mode: unit = u32 (4 bytes) — identical index math.
// 8 units per thread, fully staged -> deep MLP, linear instantaneous stream.
// ---------------------------------------------------------------------------
__global__ __launch_bounds__(256) void compress_kernel(
        const void* __restrict__ masks, u64* __restrict__ rp) {
    const bool words = is_word_fmt((const u32*)masks);
    const int T    = blockIdx.x * 256 + threadIdx.x;   // 0..NTHR-1
    const int lane = threadIdx.x & 63;

    if (words) {
        const uint4* src = (const uint4*)masks;        // 4M uint4
        uint4 v[8];
#pragma unroll
        for (int it = 0; it < 8; ++it)
            v[it] = src[(size_t)T + (size_t)it * NTHR];
#pragma unroll
        for (int it = 0; it < 8; ++it) {
            const u64 b0 = __ballot(v[it].x != 0u);
            const u64 b1 = __ballot(v[it].y != 0u);
            const u64 b2 = __ballot(v[it].z != 0u);
            const u64 b3 = __ballot(v[it].w != 0u);
            const size_t chunk = ((size_t)T + (size_t)it * NTHR) >> 6;
            if (lane < 4) {
                const u64 bb = lane == 0 ? b0 : lane == 1 ? b1
                             : lane == 2 ? b2 : b3;
                rp[chunk * 4 + lane] = bb;
            }
        }
    } else {
        const u32* src = (const u32*)masks;            // 4M u32 (byte mode)
        u32 v[8];
#pragma unroll
        for (int it = 0; it < 8; ++it)
            v[it] = src[(size_t)T + (size_t)it * NTHR];
#pragma unroll
        for (int it = 0; it < 8; ++it) {
            const u64 b0 = __ballot((v[it] & 0x000000FFu) != 0u);
            const u64 b1 = __ballot((v[it] & 0x0000FF00u) != 0u);
            const u64 b2 = __ballot((v[it] & 0x00FF0000u) != 0u);
            const u64 b3 = __ballot((v[it] & 0xFF000000u) != 0u);
            const size_t chunk = ((size_t)T + (size_t)it * NTHR) >> 6;
            if (lane < 4) {
                const u64 bb = lane == 0 ? b0 : lane == 1 ? b1
                             : lane == 2 ? b2 : b3;
                rp[chunk * 4 + lane] = bb;
            }
        }
    }
}

// ---------------------------------------------------------------------------
// K2: 64x64 bit-tile transpose rp -> canonical mp[w][o] (+ x pack fused).
// blocks 0..1023: one tile per wave. Tile (w, oseg): columns o0=oseg*64.
//   Row i = w*64+r columns [o0,o0+64) live in rp[i*64 + jbase + (d&3)]
//   bit (Lbase + (d>>2)), jbase=(o0>>8)*4, Lbase=(o0&255)>>2.
//   Lane r holds row r's 4 words; 64 ballots build the 64 column words;
//   lane d keeps ballot d; coalesced u64 store.
// blocks 1024..1039: x pack via wave ballot (64 waves x 64 words).
// ---------------------------------------------------------------------------
__global__ __launch_bounds__(256) void transpose_kernel(
        const u64* __restrict__ rp, const void* __restrict__ x,
        u64* __restrict__ mp, u64* __restrict__ xp) {
    const int bid = blockIdx.x;
    if (bid < 1024) {
        const int wg   = bid * 4 + (threadIdx.x >> 6);   // 0..4095
        const int w    = wg >> 6;                        // 0..63
        const int oseg = wg & 63;                        // 0..63
        const int r    = threadIdx.x & 63;               // row within group
        const int o0   = oseg * 64;
        const int jbase = (o0 >> 8) * 4;
        const int Lbase = (o0 & 255) >> 2;               // 0,16,32,48

        const u64* rowp = rp + (size_t)(w * 64 + r) * 64 + jbase;
        const u64 rw0 = rowp[0];
        const u64 rw1 = rowp[1];
        const u64 rw2 = rowp[2];
        const u64 rw3 = rowp[3];

        u64 mine = 0;
#pragma unroll
        for (int d = 0; d < 64; ++d) {
            const u64 srcw = (d & 3) == 0 ? rw0 : (d & 3) == 1 ? rw1
                           : (d & 3) == 2 ? rw2 : rw3;
            const int sh = Lbase + (d >> 2);
            const u64 m = __ballot(((srcw >> sh) & 1ull) != 0ull);
            if (r == d) mine = m;
        }
        mp[(size_t)w * DIM_OUT + o0 + r] = mine;
    } else {
        // ------------------- x pack -------------------
        const bool words = is_word_fmt((const u32*)x);
        const int bxid = bid - 1024;                          // 0..15
        const int wave = bxid * 4 + (threadIdx.x >> 6);       // 0..63
        const int lane = threadIdx.x & 63;
        const int base = wave * 64;                           // word index base

#pragma unroll 16
        for (int k = 0; k < 64; ++k) {
            const int idx = base + k;                         // 0..4095
            const size_t e = (size_t)idx * 64 + lane;         // element index
            bool pred;
            if (words) pred = ((const u32*)x)[e] != 0u;
            else       pred = ((const uint8_t*)x)[e] != 0u;
            const u64 m = __ballot(pred);
            if (lane == 0) xp[idx] = m;
        }
    }
}

// ---------------------------------------------------------------------------
// K3: out[b][o] = ((4096 - sum_w popc(xp[b][w] ^ mp[w][o])) > thr[o]) ? 1 : 0
// Output dtype INT32 (bool output -> int32 harness path).
// Grid: (16 o-blocks, 16 b-blocks) x 256 threads; 4 batch rows per thread.
// ---------------------------------------------------------------------------
__global__ __launch_bounds__(256) void bnn_kernel(
        const u64* __restrict__ mp, const u64* __restrict__ xp,
        const int* __restrict__ thr, int* __restrict__ out) {
    const int o  = blockIdx.x * 256 + threadIdx.x;
    const int b0 = blockIdx.y * 4;

    const u64* __restrict__ x0 = xp + (size_t)(b0 + 0) * 64;
    const u64* __restrict__ x1 = xp + (size_t)(b0 + 1) * 64;
    const u64* __restrict__ x2 = xp + (size_t)(b0 + 2) * 64;
    const u64* __restrict__ x3 = xp + (size_t)(b0 + 3) * 64;

    int a0 = 0, a1 = 0, a2 = 0, a3 = 0;
#pragma unroll 16
    for (int w = 0; w < 64; ++w) {
        const u64 mw = mp[(size_t)w * DIM_OUT + o];
        a0 += __popcll(x0[w] ^ mw);
        a1 += __popcll(x1[w] ^ mw);
        a2 += __popcll(x2[w] ^ mw);
        a3 += __popcll(x3[w] ^ mw);
    }

    const int t = thr[o];
    out[(size_t)(b0 + 0) * DIM_OUT + o] = (DIM_IN - a0) > t ? 1 : 0;
    out[(size_t)(b0 + 1) * DIM_OUT + o] = (DIM_IN - a1) > t ? 1 : 0;
    out[(size_t)(b0 + 2) * DIM_OUT + o] = (DIM_IN - a2) > t ? 1 : 0;
    out[(size_t)(b0 + 3) * DIM_OUT + o] = (DIM_IN - a3) > t ? 1 : 0;
}

// ---------------------------------------------------------------------------
extern "C" void kernel_launch(void* const* d_in, const int* in_sizes, int n_in,
                              void* d_out, int out_size, void* d_ws, size_t ws_size,
                              hipStream_t stream) {
    const void* x     = d_in[0];                 // bool [64][4096]
    const void* masks = d_in[1];                 // bool [4096][4096]
    const int*  thr   = (const int*)d_in[2];     // int32 [4096]
    int* out = (int*)d_out;                      // [64][4096] int32 0/1

    u64* rp = (u64*)d_ws;                                         // 2 MiB
    u64* mp = (u64*)((char*)d_ws + (size_t)2 * 1024 * 1024);      // 2 MiB
    u64* xp = (u64*)((char*)d_ws + (size_t)4 * 1024 * 1024);      // 32 KiB

    compress_kernel <<<dim3(NBLK1), dim3(256), 0, stream>>>(masks, rp);
    transpose_kernel<<<dim3(1040),  dim3(256), 0, stream>>>(rp, x, mp, xp);
    bnn_kernel      <<<dim3(16,16), dim3(256), 0, stream>>>(mp, xp, thr, out);
}